// Round 7
// baseline (96.185 us; speedup 1.0000x reference)
//
#include <hip/hip_runtime.h>
#include <hip/hip_bf16.h>

#define NN 4096      // N = 2*B
#define BB 2048      // B
#define DD 512       // D
#define TM 64        // C tile (R7: 128 -> 64, one wave per block)
#define BK 64        // K tile
#define NTILE (NN/TM)                 // 64
#define NPAIR (NTILE*(NTILE+1)/2)     // 2080 blocks: bi <= bj

typedef __bf16 bf16x8 __attribute__((ext_vector_type(8)));
typedef float  f32x4  __attribute__((ext_vector_type(4)));

// async global->LDS, 16B per lane. LDS dest must be wave-uniform base + lane*16.
#define GLOAD_LDS16(gsrc, ldst)                                                  \
    __builtin_amdgcn_global_load_lds(                                            \
        (__attribute__((address_space(1))) void*)(gsrc),                         \
        (__attribute__((address_space(3))) void*)(ldst), 16, 0, 0)

__device__ __forceinline__ unsigned short f2bf(float x) {
    unsigned int u = __float_as_uint(x);
    unsigned int r = (u + 0x7fffu + ((u >> 16) & 1u)) >> 16;  // RNE; inputs finite
    return (unsigned short)r;
}

// ---------------------------------------------------------------------------
// Kernel A: row-normalize z = [z_i; z_j] -> bf16 zn[N][D]; also zero-inits
// rowsum[] and out[0] (stream order makes these visible to later kernels).
// ---------------------------------------------------------------------------
__global__ __launch_bounds__(256) void normalize_kernel(
        const float* __restrict__ z_i, const float* __restrict__ z_j,
        unsigned short* __restrict__ zn, float* __restrict__ rowsum,
        float* __restrict__ out) {
    if (threadIdx.x < 4) rowsum[blockIdx.x * 4 + threadIdx.x] = 0.f;
    if (blockIdx.x == 0 && threadIdx.x == 0) out[0] = 0.f;

    int row  = blockIdx.x * 4 + (threadIdx.x >> 6);
    int lane = threadIdx.x & 63;
    const float* src = (row < BB) ? (z_i + (size_t)row * DD)
                                  : (z_j + (size_t)(row - BB) * DD);
    const float4* s4 = (const float4*)src;
    float4 v0 = s4[lane * 2 + 0];
    float4 v1 = s4[lane * 2 + 1];
    float ss = v0.x*v0.x + v0.y*v0.y + v0.z*v0.z + v0.w*v0.w
             + v1.x*v1.x + v1.y*v1.y + v1.z*v1.z + v1.w*v1.w;
    #pragma unroll
    for (int off = 1; off < 64; off <<= 1) ss += __shfl_xor(ss, off, 64);
    float inv = 1.0f / fmaxf(sqrtf(ss), 1e-8f);

    float f[8] = {v0.x, v0.y, v0.z, v0.w, v1.x, v1.y, v1.z, v1.w};
    unsigned int p[4];
    #pragma unroll
    for (int k = 0; k < 4; ++k) {
        unsigned int lo = f2bf(f[2*k] * inv);
        unsigned int hi = f2bf(f[2*k+1] * inv);
        p[k] = lo | (hi << 16);
    }
    uint4 outv = make_uint4(p[0], p[1], p[2], p[3]);
    *(uint4*)(zn + (size_t)row * DD + lane * 8) = outv;
}

// ---------------------------------------------------------------------------
// Kernel B (R7): sim = (zn @ zn^T) * 2, upper-triangular 64x64 tiles,
// ONE WAVE PER BLOCK (2080 blocks), zero barriers.
// Per-wave double-buffered pipeline with COUNTED vmcnt (T4): stage(next)
// is issued before compute(cur); "s_waitcnt vmcnt(16)" (non-diag; 8 diag)
// only drains cur's loads while next's 16 stay in flight under the MFMAs.
// lgkmcnt(0) before each stage guards the LDS overwrite (all ds_reads of
// the buffer being re-staged have retired); sched_barrier(0) after the
// counted wait stops the scheduler hoisting consumers above it (rule 18).
// Both operands LDS-staged (R6 showed B-direct gathers lose ~7 us).
// Epilogue unchanged: atomic rowsum (R1-R4 A/B: faster than part[] scheme),
// selfsim (diag), possim (bj==bi+32).
// LDS 32 KB -> 5 blocks/CU; 2080 blocks backfill work-conservingly.
// ---------------------------------------------------------------------------
__global__ __launch_bounds__(64) void simexp_kernel(
        const unsigned short* __restrict__ zn, float* __restrict__ rowsum,
        float* __restrict__ selfsim, float* __restrict__ possim) {
    __shared__ __align__(16) unsigned short As[2][TM * BK];   // 2 x 8 KB
    __shared__ __align__(16) unsigned short Bs[2][TM * BK];   // 2 x 8 KB

    // triangular decode: p -> (bi <= bj)
    int p  = blockIdx.x;
    int bj = (int)((sqrtf(8.0f * (float)p + 1.0f) - 1.0f) * 0.5f);
    while ((bj + 1) * (bj + 2) / 2 <= p) ++bj;
    while (bj * (bj + 1) / 2 > p) --bj;
    int bi = p - bj * (bj + 1) / 2;
    const bool diag = (bi == bj);

    const int tid  = threadIdx.x;            // 0..63 — one wave
    const int lrow = tid & 15, quad = tid >> 4;

    f32x4 acc[4][4];
    #pragma unroll
    for (int i = 0; i < 4; ++i)
        #pragma unroll
        for (int j = 0; j < 4; ++j) acc[i][j] = (f32x4){0.f, 0.f, 0.f, 0.f};

    // stage one 64x64 slab pair into buffer `buf` (source-side XOR swizzle)
    auto stage = [&](int buf, int kb) {
        #pragma unroll
        for (int it = 0; it < 8; ++it) {
            int t  = it * 64 + tid;        // chunk-slot 0..511
            int r  = t >> 3;               // tile row 0..63
            int cc = t & 7;                // LDS chunk slot (8 per row)
            int sc = cc ^ (r & 7);         // global source chunk (swizzle)
            GLOAD_LDS16(zn + (size_t)(bi * TM + r) * DD + kb + sc * 8,
                        &As[buf][t * 8]);
            if (!diag)
                GLOAD_LDS16(zn + (size_t)(bj * TM + r) * DD + kb + sc * 8,
                            &Bs[buf][t * 8]);
        }
    };

    // consume buffer `buf`: 2 K=32 steps, 32 MFMA, 16 ds_read_b128
    auto compute = [&](int buf) {
        const unsigned short* Ab = As[buf];
        const unsigned short* Bb = diag ? As[buf] : Bs[buf];
        #pragma unroll
        for (int s = 0; s < 2; ++s) {
            bf16x8 a[4], b[4];
            #pragma unroll
            for (int ti = 0; ti < 4; ++ti) {
                int m = ti * 16 + lrow;
                int q = (s * 4 + quad) ^ (m & 7);
                a[ti] = *(const bf16x8*)&Ab[m * BK + q * 8];
            }
            #pragma unroll
            for (int tj = 0; tj < 4; ++tj) {
                int n = tj * 16 + lrow;
                int q = (s * 4 + quad) ^ (n & 7);
                b[tj] = *(const bf16x8*)&Bb[n * BK + q * 8];
            }
            #pragma unroll
            for (int ti = 0; ti < 4; ++ti)
                #pragma unroll
                for (int tj = 0; tj < 4; ++tj)
                    acc[ti][tj] = __builtin_amdgcn_mfma_f32_16x16x32_bf16(
                        a[ti], b[tj], acc[ti][tj], 0, 0, 0);
        }
    };

    stage(0, 0);
    #pragma unroll
    for (int ki = 0; ki < DD / BK; ++ki) {          // 8 iters, fully unrolled
        const int cur = ki & 1;
        // all ds_reads of the buffer about to be overwritten have retired
        asm volatile("s_waitcnt lgkmcnt(0)" ::: "memory");
        if (ki < DD / BK - 1) {
            stage(cur ^ 1, (ki + 1) * BK);          // issue next slab async
            if (diag) asm volatile("s_waitcnt vmcnt(8)"  ::: "memory");
            else      asm volatile("s_waitcnt vmcnt(16)" ::: "memory");
        } else {
            asm volatile("s_waitcnt vmcnt(0)" ::: "memory");
        }
        __builtin_amdgcn_sched_barrier(0);
        compute(cur);
    }

    // Epilogue. C/D layout (verified): tile row = ti*16 + quad*4 + reg,
    // tile col = tj*16 + lrow.
    float rowpart[4][4];   // [ti][reg]
    float colpart[4];      // [tj]
    #pragma unroll
    for (int i = 0; i < 4; ++i) {
        colpart[i] = 0.f;
        #pragma unroll
        for (int r = 0; r < 4; ++r) rowpart[i][r] = 0.f;
    }
    #pragma unroll
    for (int ti = 0; ti < 4; ++ti)
        #pragma unroll
        for (int tj = 0; tj < 4; ++tj)
            #pragma unroll
            for (int reg = 0; reg < 4; ++reg) {
                float e = __expf(acc[ti][tj][reg] * 2.0f);
                rowpart[ti][reg] += e;
                colpart[tj]      += e;
            }

    // row-sums: reduce over lrow (16-lane groups)
    #pragma unroll
    for (int ti = 0; ti < 4; ++ti) {
        #pragma unroll
        for (int reg = 0; reg < 4; ++reg) {
            float v = rowpart[ti][reg];
            v += __shfl_xor(v, 1, 64);
            v += __shfl_xor(v, 2, 64);
            v += __shfl_xor(v, 4, 64);
            v += __shfl_xor(v, 8, 64);
            if (lrow == 0)
                atomicAdd(&rowsum[bi * TM + ti * 16 + quad * 4 + reg], v);
        }
    }
    // col-sums -> rows of bj tile (transpose); skip on diagonal tiles
    if (!diag) {
        #pragma unroll
        for (int tj = 0; tj < 4; ++tj) {
            float v = colpart[tj];
            v += __shfl_xor(v, 16, 64);
            v += __shfl_xor(v, 32, 64);
            if (quad == 0)
                atomicAdd(&rowsum[bj * TM + tj * 16 + lrow], v);
        }
    }

    // tile-diagonal extraction: lanes with lrow>>2==quad hold element (r,r)
    // of the tile at acc[ti][ti][lrow&3], r = ti*16 + lrow.
    const bool posb = (bj == bi + NTILE / 2);   // bj == bi + 32  (col offset B)
    if ((diag || posb) && (lrow >> 2) == quad) {
        #pragma unroll
        for (int ti = 0; ti < 4; ++ti) {
            float v = 2.0f * acc[ti][ti][lrow & 3];
            int R = bi * TM + ti * 16 + lrow;
            if (diag) {
                selfsim[R] = v;
            } else {
                possim[R]      = v;   // sim[r][r+B]
                possim[R + BB] = v;   // == sim[r+B][r]
            }
        }
    }
}

// ---------------------------------------------------------------------------
// Kernel C: loss_r = log(rowsum_r - exp(selfsim_r)) - possim_r; block-reduce;
// atomicAdd(out, sum/N). 3 float reads per row — no zn traffic.
// ---------------------------------------------------------------------------
__global__ __launch_bounds__(256) void rowfinal_kernel(
        const float* __restrict__ rowsum, const float* __restrict__ selfsim,
        const float* __restrict__ possim, float* __restrict__ out) {
    __shared__ float s[256];
    int r = blockIdx.x * 256 + threadIdx.x;
    s[threadIdx.x] = logf(rowsum[r] - __expf(selfsim[r])) - possim[r];
    __syncthreads();
    #pragma unroll
    for (int off = 128; off > 0; off >>= 1) {
        if (threadIdx.x < off) s[threadIdx.x] += s[threadIdx.x + off];
        __syncthreads();
    }
    if (threadIdx.x == 0) atomicAdd(out, s[0] * (1.0f / (float)NN));
}

extern "C" void kernel_launch(void* const* d_in, const int* in_sizes, int n_in,
                              void* d_out, int out_size, void* d_ws, size_t ws_size,
                              hipStream_t stream) {
    const float* z_i = (const float*)d_in[0];
    const float* z_j = (const float*)d_in[1];
    float* out = (float*)d_out;

    unsigned short* zn = (unsigned short*)d_ws;                    // N*D bf16 = 4 MB
    float* rowsum  = (float*)((char*)d_ws + (size_t)NN * DD * 2);  // N floats
    float* selfsim = rowsum + NN;                                  // N floats
    float* possim  = selfsim + NN;                                 // N floats

    normalize_kernel<<<NN / 4, 256, 0, stream>>>(z_i, z_j, zn, rowsum, out);
    simexp_kernel<<<NPAIR, 64, 0, stream>>>(zn, rowsum, selfsim, possim);
    rowfinal_kernel<<<NN / 256, 256, 0, stream>>>(rowsum, selfsim, possim, out);
}

// Round 8
// 85.526 us; speedup vs baseline: 1.1246x; 1.1246x over previous
//
#include <hip/hip_runtime.h>
#include <hip/hip_bf16.h>

#define NN 4096      // N = 2*B
#define BB 2048      // B
#define DD 512       // D
#define TM 128       // C tile (M and N)
#define BK 64        // K tile (dbuf: 2 x (16+16) KB = 64 KB, 2 blocks/CU)
#define NTILE (NN/TM)                 // 32
#define NPAIR (NTILE*(NTILE+1)/2)     // 528 blocks: bi <= bj

typedef __bf16 bf16x8 __attribute__((ext_vector_type(8)));
typedef float  f32x4  __attribute__((ext_vector_type(4)));

// async global->LDS, 16B per lane. LDS dest must be wave-uniform base + lane*16.
#define GLOAD_LDS16(gsrc, ldst)                                                  \
    __builtin_amdgcn_global_load_lds(                                            \
        (__attribute__((address_space(1))) void*)(gsrc),                         \
        (__attribute__((address_space(3))) void*)(ldst), 16, 0, 0)

__device__ __forceinline__ unsigned short f2bf(float x) {
    unsigned int u = __float_as_uint(x);
    unsigned int r = (u + 0x7fffu + ((u >> 16) & 1u)) >> 16;  // RNE; inputs finite
    return (unsigned short)r;
}

// ---------------------------------------------------------------------------
// Kernel A: row-normalize z = [z_i; z_j] -> bf16 zn[N][D]; also zero-inits
// rowsum[] and out[0] (stream order makes these visible to later kernels).
// ---------------------------------------------------------------------------
__global__ __launch_bounds__(256) void normalize_kernel(
        const float* __restrict__ z_i, const float* __restrict__ z_j,
        unsigned short* __restrict__ zn, float* __restrict__ rowsum,
        float* __restrict__ out) {
    if (threadIdx.x < 4) rowsum[blockIdx.x * 4 + threadIdx.x] = 0.f;
    if (blockIdx.x == 0 && threadIdx.x == 0) out[0] = 0.f;

    int row  = blockIdx.x * 4 + (threadIdx.x >> 6);
    int lane = threadIdx.x & 63;
    const float* src = (row < BB) ? (z_i + (size_t)row * DD)
                                  : (z_j + (size_t)(row - BB) * DD);
    const float4* s4 = (const float4*)src;
    float4 v0 = s4[lane * 2 + 0];
    float4 v1 = s4[lane * 2 + 1];
    float ss = v0.x*v0.x + v0.y*v0.y + v0.z*v0.z + v0.w*v0.w
             + v1.x*v1.x + v1.y*v1.y + v1.z*v1.z + v1.w*v1.w;
    #pragma unroll
    for (int off = 1; off < 64; off <<= 1) ss += __shfl_xor(ss, off, 64);
    float inv = 1.0f / fmaxf(sqrtf(ss), 1e-8f);

    float f[8] = {v0.x, v0.y, v0.z, v0.w, v1.x, v1.y, v1.z, v1.w};
    unsigned int p[4];
    #pragma unroll
    for (int k = 0; k < 4; ++k) {
        unsigned int lo = f2bf(f[2*k] * inv);
        unsigned int hi = f2bf(f[2*k+1] * inv);
        p[k] = lo | (hi << 16);
    }
    uint4 outv = make_uint4(p[0], p[1], p[2], p[3]);
    *(uint4*)(zn + (size_t)row * DD + lane * 8) = outv;
}

// ---------------------------------------------------------------------------
// Kernel B (R8): sim = (zn @ zn^T) * 2, upper-triangular 128x128 tiles
// (528 blocks, 2x2 waves of 64x64 — the R5-best geometry), with a TRUE
// T4 counted-vmcnt pipeline:
//   per K-iter: stage(next buf)  [8 gload_lds/wave, 4 on diag]
//               s_waitcnt vmcnt(8|4)   <- cur's loads retired (FIFO),
//                                         next's stay IN FLIGHT
//               s_barrier               <- all waves' cur loads landed
//               compute(cur)            <- 32 MFMA + 16 ds_read_b128 /wave
//               s_waitcnt lgkmcnt(0); s_barrier  <- safe to overwrite cur
// R1's version drained vmcnt(0) via __syncthreads each step — per T4
// (m218) that nullifies the pipeline; this version never drains in-loop.
// Both operands LDS-staged (R6: B-direct gathers lose ~7 us). Atomic
// rowsum epilogue (R1-R4 A/B: part[] scheme loses ~15 us).
// LDS 64 KB -> 2 blocks/CU (same occupancy as R5).
// ---------------------------------------------------------------------------
__global__ __launch_bounds__(256) void simexp_kernel(
        const unsigned short* __restrict__ zn, float* __restrict__ rowsum,
        float* __restrict__ selfsim, float* __restrict__ possim) {
    __shared__ __align__(16) unsigned short As[2][TM * BK];   // 2 x 16 KB
    __shared__ __align__(16) unsigned short Bs[2][TM * BK];   // 2 x 16 KB

    // triangular decode: p -> (bi <= bj)
    int p  = blockIdx.x;
    int bj = (int)((sqrtf(8.0f * (float)p + 1.0f) - 1.0f) * 0.5f);
    while ((bj + 1) * (bj + 2) / 2 <= p) ++bj;
    while (bj * (bj + 1) / 2 > p) --bj;
    int bi = p - bj * (bj + 1) / 2;
    const bool diag = (bi == bj);

    const int tid  = threadIdx.x;
    const int wave = tid >> 6, lane = tid & 63;
    const int wr = wave >> 1, wc = wave & 1;   // 2x2 wave grid, 64x64 each
    const int lrow = lane & 15, quad = lane >> 4;

    f32x4 acc[4][4];
    #pragma unroll
    for (int i = 0; i < 4; ++i)
        #pragma unroll
        for (int j = 0; j < 4; ++j) acc[i][j] = (f32x4){0.f, 0.f, 0.f, 0.f};

    // stage one BK-slab pair into buffer `buf` (source-side XOR swizzle)
    auto stage = [&](int buf, int kb) {
        #pragma unroll
        for (int it = 0; it < 4; ++it) {
            int t  = it * 256 + tid;       // chunk-slot 0..1023
            int r  = t >> 3;               // tile row 0..127
            int cc = t & 7;                // LDS chunk slot (8 per row)
            int sc = cc ^ (r & 7);         // global source chunk (swizzle)
            GLOAD_LDS16(zn + (size_t)(bi * TM + r) * DD + kb + sc * 8,
                        &As[buf][t * 8]);
            if (!diag)
                GLOAD_LDS16(zn + (size_t)(bj * TM + r) * DD + kb + sc * 8,
                            &Bs[buf][t * 8]);
        }
    };

    // consume buffer `buf`: 2 K=32 steps, 32 MFMA, 16 ds_read_b128 per wave
    auto compute = [&](int buf) {
        const unsigned short* Ab = As[buf];
        const unsigned short* Bb = diag ? As[buf] : Bs[buf];
        #pragma unroll
        for (int s = 0; s < 2; ++s) {
            bf16x8 a[4], b[4];
            #pragma unroll
            for (int ti = 0; ti < 4; ++ti) {
                int m = wr * 64 + ti * 16 + lrow;
                int q = (s * 4 + quad) ^ (m & 7);
                a[ti] = *(const bf16x8*)&Ab[m * BK + q * 8];
            }
            #pragma unroll
            for (int tj = 0; tj < 4; ++tj) {
                int n = wc * 64 + tj * 16 + lrow;
                int q = (s * 4 + quad) ^ (n & 7);
                b[tj] = *(const bf16x8*)&Bb[n * BK + q * 8];
            }
            #pragma unroll
            for (int ti = 0; ti < 4; ++ti)
                #pragma unroll
                for (int tj = 0; tj < 4; ++tj)
                    acc[ti][tj] = __builtin_amdgcn_mfma_f32_16x16x32_bf16(
                        a[ti], b[tj], acc[ti][tj], 0, 0, 0);
        }
    };

    stage(0, 0);
    #pragma unroll
    for (int ki = 0; ki < DD / BK; ++ki) {          // 8 iters, unrolled
        const int cur = ki & 1;
        if (ki < DD / BK - 1) {
            stage(cur ^ 1, (ki + 1) * BK);          // prefetch next slab
            // counted wait: cur's loads (issued first, FIFO) retired;
            // next's 8 (4 diag) remain in flight under compute(cur)
            if (diag) asm volatile("s_waitcnt vmcnt(4)" ::: "memory");
            else      asm volatile("s_waitcnt vmcnt(8)" ::: "memory");
        } else {
            asm volatile("s_waitcnt vmcnt(0)" ::: "memory");
        }
        __builtin_amdgcn_s_barrier();               // all waves: cur landed
        __builtin_amdgcn_sched_barrier(0);          // rule 18: no hoisting
        compute(cur);
        // all this wave's ds_reads of cur retired (MFMA consumed them);
        // explicit drain + barrier before anyone overwrites cur next iter
        asm volatile("s_waitcnt lgkmcnt(0)" ::: "memory");
        __builtin_amdgcn_s_barrier();
    }

    // Epilogue. C/D layout (verified, absmax 0.0 in R0/R1):
    //   tile row = wr*64 + ti*16 + quad*4 + reg, tile col = wc*64 + tj*16 + lrow
    float rowpart[4][4];   // [ti][reg]
    float colpart[4];      // [tj]
    #pragma unroll
    for (int i = 0; i < 4; ++i) {
        colpart[i] = 0.f;
        #pragma unroll
        for (int r = 0; r < 4; ++r) rowpart[i][r] = 0.f;
    }
    #pragma unroll
    for (int ti = 0; ti < 4; ++ti)
        #pragma unroll
        for (int tj = 0; tj < 4; ++tj)
            #pragma unroll
            for (int reg = 0; reg < 4; ++reg) {
                float e = __expf(acc[ti][tj][reg] * 2.0f);
                rowpart[ti][reg] += e;
                colpart[tj]      += e;
            }

    // row-sums: reduce over lrow (16-lane groups)
    #pragma unroll
    for (int ti = 0; ti < 4; ++ti) {
        #pragma unroll
        for (int reg = 0; reg < 4; ++reg) {
            float v = rowpart[ti][reg];
            v += __shfl_xor(v, 1, 64);
            v += __shfl_xor(v, 2, 64);
            v += __shfl_xor(v, 4, 64);
            v += __shfl_xor(v, 8, 64);
            if (lrow == 0)
                atomicAdd(&rowsum[bi * TM + wr * 64 + ti * 16 + quad * 4 + reg], v);
        }
    }
    // col-sums -> rows of bj tile (transpose); skip on diagonal tiles
    if (!diag) {
        #pragma unroll
        for (int tj = 0; tj < 4; ++tj) {
            float v = colpart[tj];
            v += __shfl_xor(v, 16, 64);
            v += __shfl_xor(v, 32, 64);
            if (quad == 0)
                atomicAdd(&rowsum[bj * TM + wc * 64 + tj * 16 + lrow], v);
        }
    }

    // tile-diagonal extraction: lanes lrow>>2==quad in waves wr==wc hold
    // element (r, r) of the tile at acc[ti][ti][lrow&3], r = wr*64+ti*16+lrow.
    const bool posb = (bj == bi + NTILE / 2);   // bj == bi + 16  (col offset B)
    if ((diag || posb) && wr == wc && (lrow >> 2) == quad) {
        #pragma unroll
        for (int ti = 0; ti < 4; ++ti) {
            float v = 2.0f * acc[ti][ti][lrow & 3];
            int R = bi * TM + wr * 64 + ti * 16 + lrow;
            if (diag) {
                selfsim[R] = v;
            } else {
                possim[R]      = v;   // sim[r][r+B]
                possim[R + BB] = v;   // == sim[r+B][r]
            }
        }
    }
}

// ---------------------------------------------------------------------------
// Kernel C: loss_r = log(rowsum_r - exp(selfsim_r)) - possim_r; block-reduce;
// atomicAdd(out, sum/N). 3 float reads per row — no zn traffic.
// ---------------------------------------------------------------------------
__global__ __launch_bounds__(256) void rowfinal_kernel(
        const float* __restrict__ rowsum, const float* __restrict__ selfsim,
        const float* __restrict__ possim, float* __restrict__ out) {
    __shared__ float s[256];
    int r = blockIdx.x * 256 + threadIdx.x;
    s[threadIdx.x] = logf(rowsum[r] - __expf(selfsim[r])) - possim[r];
    __syncthreads();
    #pragma unroll
    for (int off = 128; off > 0; off >>= 1) {
        if (threadIdx.x < off) s[threadIdx.x] += s[threadIdx.x + off];
        __syncthreads();
    }
    if (threadIdx.x == 0) atomicAdd(out, s[0] * (1.0f / (float)NN));
}

extern "C" void kernel_launch(void* const* d_in, const int* in_sizes, int n_in,
                              void* d_out, int out_size, void* d_ws, size_t ws_size,
                              hipStream_t stream) {
    const float* z_i = (const float*)d_in[0];
    const float* z_j = (const float*)d_in[1];
    float* out = (float*)d_out;

    unsigned short* zn = (unsigned short*)d_ws;                    // N*D bf16 = 4 MB
    float* rowsum  = (float*)((char*)d_ws + (size_t)NN * DD * 2);  // N floats
    float* selfsim = rowsum + NN;                                  // N floats
    float* possim  = selfsim + NN;                                 // N floats

    normalize_kernel<<<NN / 4, 256, 0, stream>>>(z_i, z_j, zn, rowsum, out);
    simexp_kernel<<<NPAIR, 256, 0, stream>>>(zn, rowsum, selfsim, possim);
    rowfinal_kernel<<<NN / 256, 256, 0, stream>>>(rowsum, selfsim, possim, out);
}